// Round 5
// baseline (9294.586 us; speedup 1.0000x reference)
//
#include <hip/hip_runtime.h>
#include <hip/hip_bf16.h>

#define Bb 32
#define Tt 1024
#define Dd 768
#define Hh 768
#define NGRP 2       // independent batch groups (no cross-group sync)
#define BPG 96       // blocks per group
#define GB  16       // batches per group
#define CPB 8        // h-columns per block (96*8 = 768)
#define NTHREADS 192 // 3 waves = 3 N-tiles exactly

#define NWELE ((size_t)6 * Hh * Dd)   // W_in elements
#define NSELE ((size_t)5 * Hh * Hh)   // W_s elements
#define WS_NB    4096
#define WS_FLG   8192                 // 2 groups x 256 wave-flag slots
#define WS_HBOFF (WS_NB + WS_FLG)
#define HBSZ     (GB * Hh * 2)        // 24576 B per h buffer
#define WS_WGT   (WS_HBOFF + 4 * HBSZ)
#define WS_NEED  (WS_WGT + (NWELE + NSELE) * 2)

typedef short short8 __attribute__((ext_vector_type(8)));
typedef float f4 __attribute__((ext_vector_type(4)));

__device__ __forceinline__ float bf2f(ushort u) {
    unsigned x = (unsigned)u << 16;
    return __builtin_bit_cast(float, x);
}
__device__ __forceinline__ ushort f2bf(float f) {
    unsigned u = __builtin_bit_cast(unsigned, f);
    return (ushort)((u + 0x7fffu + ((u >> 16) & 1u)) >> 16);
}
__device__ __forceinline__ float sigm(float x) { return 1.0f / (1.0f + __expf(-x)); }
__device__ __forceinline__ float tanh_(float x) {
    float e = __expf(2.0f * x);
    return 1.0f - 2.0f / (e + 1.0f);
}
// pack 8 f32 (two uint4 bit-images) -> 8 bf16 in one uint4
__device__ __forceinline__ uint4 packbf(uint4 a, uint4 b) {
    uint4 v;
    v.x = (unsigned)f2bf(__builtin_bit_cast(float, a.x))
        | ((unsigned)f2bf(__builtin_bit_cast(float, a.y)) << 16);
    v.y = (unsigned)f2bf(__builtin_bit_cast(float, a.z))
        | ((unsigned)f2bf(__builtin_bit_cast(float, a.w)) << 16);
    v.z = (unsigned)f2bf(__builtin_bit_cast(float, b.x))
        | ((unsigned)f2bf(__builtin_bit_cast(float, b.y)) << 16);
    v.w = (unsigned)f2bf(__builtin_bit_cast(float, b.z))
        | ((unsigned)f2bf(__builtin_bit_cast(float, b.w)) << 16);
    return v;
}

// LDS-only barrier: orders ds_write -> ds_read without draining vmcnt
// (plain __syncthreads emits s_waitcnt vmcnt(0), putting y/h store acks on
// the critical chain). Guide §5/T4: counted-vmem stays in flight.
__device__ __forceinline__ void bar_lgkm() {
    __asm__ volatile("s_waitcnt lgkmcnt(0)" ::: "memory");
    __builtin_amdgcn_s_barrier();
    __builtin_amdgcn_sched_barrier(0);
}

// nb[t] = number of active batches at step t (lengths sorted descending)
__global__ void prep_nb(const int* __restrict__ len, int* __restrict__ nbArr) {
    int t = blockIdx.x * 256 + threadIdx.x;
    if (t < Tt) {
        int c = 0;
#pragma unroll
        for (int b = 0; b < Bb; ++b) c += (len[b] > t) ? 1 : 0;
        nbArr[t] = c;
    }
}

// Convert (or copy) W_in and W_s into a packed bf16 image in ws.
__global__ void conv_w(const void* __restrict__ Win, const void* __restrict__ Ws,
                       const void* __restrict__ bs, ushort* __restrict__ wOut) {
    const bool isbf = (((const unsigned*)bs)[384] != 0u);
    size_t i = ((size_t)blockIdx.x * 256 + threadIdx.x) * 8;
    if (i >= NWELE + NSELE) return;
    const void* src = (i < NWELE) ? Win : Ws;
    size_t off = (i < NWELE) ? i : (i - NWELE);
    if (isbf) {
        *(uint4*)(wOut + i) = *(const uint4*)((const ushort*)src + off);
    } else {
        const f4* s = (const f4*)((const float*)src + off);
        f4 a = s[0], c = s[1];
        uint4 v;
        v.x = (unsigned)f2bf(a[0]) | ((unsigned)f2bf(a[1]) << 16);
        v.y = (unsigned)f2bf(a[2]) | ((unsigned)f2bf(a[3]) << 16);
        v.z = (unsigned)f2bf(c[0]) | ((unsigned)f2bf(c[1]) << 16);
        v.w = (unsigned)f2bf(c[2]) | ((unsigned)f2bf(c[3]) << 16);
        *(uint4*)(wOut + i) = v;
    }
}

// Persistent fused LSTM. R5 = R4 structure (h-dependent work only on the
// flag-to-flag chain) with: (1) spill-free x prefetch -- 8 NAMED uint4 regs
// holding pre-packed bf16 (f32 converted at load), no arrays -> no scratch;
// (2) lgkm-only barriers (no vmcnt drain at b1/b2); (3) y stored right after
// the flag so its ack retires during slack work.
__global__ __launch_bounds__(NTHREADS, 1) void lstm_main(
    const void* __restrict__ inp, const void* __restrict__ bin,
    const void* __restrict__ bs, const int* __restrict__ len,
    void* __restrict__ y, const int* __restrict__ nbArr,
    unsigned* flags, ushort* hbAll, const ushort* __restrict__ wbf)
{
    __shared__ ushort wsL[48 * 776];     // W_s slice, rows 40..47 zero (74.5 KB)
    __shared__ ushort hA[GB * 776];      // staged x K-operand (24.8 KB, single buf)
    __shared__ float accT[3][16][16];    // 3 N-tile results (3 KB)

    const bool isbf = (((const unsigned*)bs)[384] != 0u);

    const int tid  = threadIdx.x;
    const int lane = tid & 63;
    const int wave = tid >> 6;           // 0..2 = N-tile
    const int g    = blockIdx.x & 1;     // group
    const int w    = blockIdx.x >> 1;    // block index within group, 0..95
    const int n0   = w * CPB;

    // --- W_s slice into LDS: zero all 48 rows, fill rows 0..39 ---
    for (int i = tid; i < 48 * 776 / 8; i += NTHREADS)
        *(uint4*)&wsL[i * 8] = uint4{0u, 0u, 0u, 0u};
    const ushort* wbfS = wbf + NWELE;
    __syncthreads();
    for (int i = tid; i < 40 * 96; i += NTHREADS) {
        int c = i / 96, ch = i - c * 96;
        *(uint4*)&wsL[c * 776 + ch * 8] =
            *(const uint4*)(wbfS + ((size_t)((c >> 3) * Hh + n0 + (c & 7))) * Hh + ch * 8);
    }

    // --- per-thread combine constants ---
    float B0 = 0, B1 = 0, B2 = 0, B3 = 0, B4 = 0, B5 = 0, cReg = 0.0f;
    int lenb = 0;
    if (tid < 128) {
        int j = tid & 7, n = n0 + j;
        if (isbf) {
            const ushort* bi = (const ushort*)bin; const ushort* bsp = (const ushort*)bs;
            B0 = bf2f(bi[0 * Hh + n]) + bf2f(bsp[0 * Hh + n]);
            B1 = bf2f(bi[1 * Hh + n]) + bf2f(bsp[1 * Hh + n]);
            B2 = bf2f(bi[2 * Hh + n]) + bf2f(bsp[2 * Hh + n]);
            B3 = bf2f(bi[3 * Hh + n]) + bf2f(bsp[3 * Hh + n]);
            B4 = bf2f(bi[4 * Hh + n]) + bf2f(bsp[4 * Hh + n]);
            B5 = bf2f(bi[5 * Hh + n]);
        } else {
            const float* bi = (const float*)bin; const float* bsp = (const float*)bs;
            B0 = bi[0 * Hh + n] + bsp[0 * Hh + n];
            B1 = bi[1 * Hh + n] + bsp[1 * Hh + n];
            B2 = bi[2 * Hh + n] + bsp[2 * Hh + n];
            B3 = bi[3 * Hh + n] + bsp[3 * Hh + n];
            B4 = bi[4 * Hh + n] + bsp[4 * Hh + n];
            B5 = bi[5 * Hh + n];
        }
        lenb = len[g * GB + (tid >> 3)];
    }

    // --- MFMA fragment addressing ---
    const int kq = (lane >> 4) << 3;
    const ushort* aP = &hA[(lane & 15) * 776 + kq];
    // A (h-half): DIRECT from global h buffer, u64 offset (4*kb+(lane>>4))*32+(lane&15)*2
    const int aoff = ((lane >> 4) * 32) + ((lane & 15) * 2);
    // B (x-half): W_in row for col cc = wave*16+(lane&15): gate=cc>>3, j=cc&7
    const int cc = wave * 16 + (lane & 15);
    const uint4* bPx = (const uint4*)(wbf + ((size_t)((cc >> 3) * Hh + n0 + (cc & 7))) * Dd + kq);
    // B (h-half): from LDS W_s slice, row cc (rows 40..47 are zeros)
    const ushort* wsP = &wsL[cc * 776 + kq];

    unsigned* wflg = flags + g * 256;    // 192 wave-flags (2 per block)
    ushort* hb[2] = {hbAll + (g * 2 + 0) * (HBSZ / 2),
                     hbAll + (g * 2 + 1) * (HBSZ / 2)};
    long gmax = (1L << 22);

    // --- x prefetch: 8 named uint4 regs, always packed bf16 (no spill) ---
    // chunk ii covers (row, c8): i = tid + ii*NTHREADS; row=i/96, c8=i%96
    int r0_ = (tid + 0 * NTHREADS) / 96, c0_ = (tid + 0 * NTHREADS) % 96;
    int r1_ = (tid + 1 * NTHREADS) / 96, c1_ = (tid + 1 * NTHREADS) % 96;
    int r2_ = (tid + 2 * NTHREADS) / 96, c2_ = (tid + 2 * NTHREADS) % 96;
    int r3_ = (tid + 3 * NTHREADS) / 96, c3_ = (tid + 3 * NTHREADS) % 96;
    int r4_ = (tid + 4 * NTHREADS) / 96, c4_ = (tid + 4 * NTHREADS) % 96;
    int r5_ = (tid + 5 * NTHREADS) / 96, c5_ = (tid + 5 * NTHREADS) % 96;
    int r6_ = (tid + 6 * NTHREADS) / 96, c6_ = (tid + 6 * NTHREADS) % 96;
    int r7_ = (tid + 7 * NTHREADS) / 96, c7_ = (tid + 7 * NTHREADS) % 96;
    // element offsets (t-independent part) into x, and LDS element offsets
    size_t sE0 = ((size_t)(g * GB + r0_) * Tt) * Dd + c0_ * 8;
    size_t sE1 = ((size_t)(g * GB + r1_) * Tt) * Dd + c1_ * 8;
    size_t sE2 = ((size_t)(g * GB + r2_) * Tt) * Dd + c2_ * 8;
    size_t sE3 = ((size_t)(g * GB + r3_) * Tt) * Dd + c3_ * 8;
    size_t sE4 = ((size_t)(g * GB + r4_) * Tt) * Dd + c4_ * 8;
    size_t sE5 = ((size_t)(g * GB + r5_) * Tt) * Dd + c5_ * 8;
    size_t sE6 = ((size_t)(g * GB + r6_) * Tt) * Dd + c6_ * 8;
    size_t sE7 = ((size_t)(g * GB + r7_) * Tt) * Dd + c7_ * 8;
    int lo0 = r0_ * 776 + c0_ * 8, lo1 = r1_ * 776 + c1_ * 8;
    int lo2 = r2_ * 776 + c2_ * 8, lo3 = r3_ * 776 + c3_ * 8;
    int lo4 = r4_ * 776 + c4_ * 8, lo5 = r5_ * 776 + c5_ * 8;
    int lo6 = r6_ * 776 + c6_ * 8, lo7 = r7_ * 776 + c7_ * 8;

    uint4 pf0, pf1, pf2, pf3, pf4, pf5, pf6, pf7;

#define PF_ONE(dst, sE, tn) do {                                              \
        if (isbf) {                                                           \
            dst = *(const uint4*)((const ushort*)inp + sE + (size_t)(tn) * Dd); \
        } else {                                                              \
            const uint4* s_ = (const uint4*)((const float*)inp + sE + (size_t)(tn) * Dd); \
            uint4 a_ = s_[0], b_ = s_[1];                                     \
            dst = packbf(a_, b_);                                             \
        }                                                                     \
    } while (0)

#define PF_ISSUE(tn) do {                                                     \
        PF_ONE(pf0, sE0, tn); PF_ONE(pf1, sE1, tn);                           \
        PF_ONE(pf2, sE2, tn); PF_ONE(pf3, sE3, tn);                           \
        PF_ONE(pf4, sE4, tn); PF_ONE(pf5, sE5, tn);                           \
        PF_ONE(pf6, sE6, tn); PF_ONE(pf7, sE7, tn);                           \
    } while (0)

#define PF_WRITE() do {                                                       \
        *(uint4*)&hA[lo0] = pf0; *(uint4*)&hA[lo1] = pf1;                     \
        *(uint4*)&hA[lo2] = pf2; *(uint4*)&hA[lo3] = pf3;                     \
        *(uint4*)&hA[lo4] = pf4; *(uint4*)&hA[lo5] = pf5;                     \
        *(uint4*)&hA[lo6] = pf6; *(uint4*)&hA[lo7] = pf7;                     \
    } while (0)

    // --- prologue: stage x_0, x-GEMM(0), prefetch x_1 ---
    PF_ISSUE(0);
    PF_WRITE();
    __syncthreads();                     // hA(x_0) + wsL ready

    f4 acc0 = {0, 0, 0, 0}, acc1 = {0, 0, 0, 0};
    f4 acc2 = {0, 0, 0, 0}, acc3 = {0, 0, 0, 0};
#pragma unroll
    for (int kb = 0; kb < 24; ++kb) {
        short8 a = __builtin_bit_cast(short8, *(const uint4*)(aP + kb * 32));
        short8 b = __builtin_bit_cast(short8, bPx[kb * 4]);
        switch (kb & 3) {
        case 0: acc0 = __builtin_amdgcn_mfma_f32_16x16x32_bf16(a, b, acc0, 0, 0, 0); break;
        case 1: acc1 = __builtin_amdgcn_mfma_f32_16x16x32_bf16(a, b, acc1, 0, 0, 0); break;
        case 2: acc2 = __builtin_amdgcn_mfma_f32_16x16x32_bf16(a, b, acc2, 0, 0, 0); break;
        default: acc3 = __builtin_amdgcn_mfma_f32_16x16x32_bf16(a, b, acc3, 0, 0, 0); break;
        }
    }
    PF_ISSUE(1);
    __builtin_amdgcn_sched_barrier(0);

    int tDone = Tt;
    for (int t = 0; t < Tt; ++t) {
        int nbg = nbArr[t] - g * GB;
        nbg = nbg < 0 ? 0 : (nbg > GB ? GB : nbg);
        if (nbg == 0) { tDone = t; break; }

        // ---- poll: all waves self-release on 192 wave-flags (3 lines) ----
        if (t > 0) {
            const unsigned target = (unsigned)t;
            long guard = 0;
            for (;;) {
                unsigned f0 = __hip_atomic_load(wflg + lane, __ATOMIC_RELAXED,
                                                __HIP_MEMORY_SCOPE_AGENT);
                unsigned f1 = __hip_atomic_load(wflg + 64 + lane, __ATOMIC_RELAXED,
                                                __HIP_MEMORY_SCOPE_AGENT);
                unsigned f2 = __hip_atomic_load(wflg + 128 + lane, __ATOMIC_RELAXED,
                                                __HIP_MEMORY_SCOPE_AGENT);
                bool ok = (f0 >= target) && (f1 >= target) && (f2 >= target);
                if (__all(ok)) break;
                if (++guard > gmax) break;
                __builtin_amdgcn_s_sleep(1);
            }
        }
        __asm__ volatile("" ::: "memory");

        // ---- ps-GEMM: A-fragments straight from the global h buffer ----
        {
            const unsigned long long* aB = (const unsigned long long*)hb[t & 1];
#pragma unroll
            for (int kb = 0; kb < 24; ++kb) {
                unsigned long long v0 = __hip_atomic_load(aB + kb * 128 + aoff,
                                                          __ATOMIC_RELAXED,
                                                          __HIP_MEMORY_SCOPE_AGENT);
                unsigned long long v1 = __hip_atomic_load(aB + kb * 128 + aoff + 1,
                                                          __ATOMIC_RELAXED,
                                                          __HIP_MEMORY_SCOPE_AGENT);
                short8 a;
                __builtin_memcpy(&a, &v0, 8);
                __builtin_memcpy((char*)&a + 8, &v1, 8);
                short8 b = __builtin_bit_cast(short8, *(const uint4*)(wsP + kb * 32));
                switch (kb & 3) {
                case 0: acc0 = __builtin_amdgcn_mfma_f32_16x16x32_bf16(a, b, acc0, 0, 0, 0); break;
                case 1: acc1 = __builtin_amdgcn_mfma_f32_16x16x32_bf16(a, b, acc1, 0, 0, 0); break;
                case 2: acc2 = __builtin_amdgcn_mfma_f32_16x16x32_bf16(a, b, acc2, 0, 0, 0); break;
                default: acc3 = __builtin_amdgcn_mfma_f32_16x16x32_bf16(a, b, acc3, 0, 0, 0); break;
                }
            }
        }
        {
            f4 s = (acc0 + acc1) + (acc2 + acc3);
            int r0 = (lane >> 4) * 4, col = lane & 15;
#pragma unroll
            for (int i = 0; i < 4; ++i) accT[wave][r0 + i][col] = s[i];
        }
        bar_lgkm();        // b2: accT ready (LDS-only; no vmcnt drain)

        // ---- combine + publish + wave-autonomous release + y store ----
        if (tid < 128) {
            int b = tid >> 3, j = tid & 7;
            float v0 = accT[(0 * 8 + j) >> 4][b][(0 * 8 + j) & 15];
            float v1 = accT[(1 * 8 + j) >> 4][b][(1 * 8 + j) & 15];
            float v2 = accT[(2 * 8 + j) >> 4][b][(2 * 8 + j) & 15];
            float v3 = accT[(3 * 8 + j) >> 4][b][(3 * 8 + j) & 15];
            float v4 = accT[(4 * 8 + j) >> 4][b][(4 * 8 + j) & 15];
            float v5 = accT[(5 * 8 + j) >> 4][b][(5 * 8 + j) & 15];
            float ii = sigm(v0 + B0);
            float ff = sigm(v1 + B1);
            float gg = tanh_(v2 + B2);
            float oo = sigm(v3 + B3);
            float hw = sigm(v4 + B4);
            float p5 = v5 + B5;
            float cn = ii * gg + ff * cReg;
            float outv = oo * tanh_(cn);
            outv = hw * outv + (1.0f - hw) * p5;
            bool act = t < lenb;
            if (act) cReg = cn;

            // gather the 4-lane subgroup's outv (f32) once; reuse for h and y
            int lane6 = tid & 63;
            int g0 = lane6 & ~3;
            float f0v = __shfl(outv, g0 + 0);
            float f1v = __shfl(outv, g0 + 1);
            float f2v = __shfl(outv, g0 + 2);
            float f3v = __shfl(outv, g0 + 3);
            if ((lane6 & 3) == 0 && act) {
                unsigned long long vv = (unsigned long long)f2bf(f0v)
                    | ((unsigned long long)f2bf(f1v) << 16)
                    | ((unsigned long long)f2bf(f2v) << 32)
                    | ((unsigned long long)f2bf(f3v) << 48);
                __hip_atomic_store(
                    (unsigned long long*)(hb[(t & 1) ^ 1] + w * 128 + b * 8 + j),
                    vv, __ATOMIC_RELAXED, __HIP_MEMORY_SCOPE_AGENT);
            }
            // wave-autonomous release: drain own h-store, set own wave-flag
            __asm__ volatile("s_waitcnt vmcnt(0)" ::: "memory");
            if (lane6 == 0)
                __hip_atomic_store(wflg + w * 2 + wave, (unsigned)(t + 1),
                                   __ATOMIC_RELAXED, __HIP_MEMORY_SCOPE_AGENT);

            // y store RIGHT AFTER flag: ack retires during slack work below
            if ((lane6 & 3) == 0) {
                size_t oiY = ((size_t)(g * GB + b) * Tt + t) * Hh + n0 + j;
                float y0 = act ? f0v : 0.0f, y1 = act ? f1v : 0.0f;
                float y2 = act ? f2v : 0.0f, y3 = act ? f3v : 0.0f;
                if (isbf) {
                    unsigned long long vv = (unsigned long long)f2bf(y0)
                        | ((unsigned long long)f2bf(y1) << 16)
                        | ((unsigned long long)f2bf(y2) << 32)
                        | ((unsigned long long)f2bf(y3) << 48);
                    *(unsigned long long*)((ushort*)y + oiY) = vv;
                } else {
                    *(f4*)((float*)y + oiY) = f4{y0, y1, y2, y3};
                }
            }
        }

        // ---- post-flag slack work: x_{t+1} -> LDS ----
        if (t + 1 < Tt) PF_WRITE();
        bar_lgkm();        // b1: hA(x_{t+1}) ready (LDS-only; no vmcnt drain)

        // ---- x-GEMM for t+1 (rides the wait slack of the next poll) ----
        acc0 = f4{0, 0, 0, 0}; acc1 = f4{0, 0, 0, 0};
        acc2 = f4{0, 0, 0, 0}; acc3 = f4{0, 0, 0, 0};
        if (t + 1 < Tt) {
#pragma unroll
            for (int kb = 0; kb < 24; ++kb) {
                short8 a = __builtin_bit_cast(short8, *(const uint4*)(aP + kb * 32));
                short8 b = __builtin_bit_cast(short8, bPx[kb * 4]);
                switch (kb & 3) {
                case 0: acc0 = __builtin_amdgcn_mfma_f32_16x16x32_bf16(a, b, acc0, 0, 0, 0); break;
                case 1: acc1 = __builtin_amdgcn_mfma_f32_16x16x32_bf16(a, b, acc1, 0, 0, 0); break;
                case 2: acc2 = __builtin_amdgcn_mfma_f32_16x16x32_bf16(a, b, acc2, 0, 0, 0); break;
                default: acc3 = __builtin_amdgcn_mfma_f32_16x16x32_bf16(a, b, acc3, 0, 0, 0); break;
                }
            }
        }
        // ---- prefetch x_{t+2} into named regs (packed bf16, no spill) ----
        if (t + 2 < Tt) PF_ISSUE(t + 2);
        __builtin_amdgcn_sched_barrier(0);
    }

    // ---- tail: group finished -> zero its remaining y cells ----
    if (tid < 128) {
        int b = tid >> 3, j = tid & 7;
        for (int t = tDone; t < Tt; ++t) {
            size_t oi = ((size_t)(g * GB + b) * Tt + t) * Hh + n0 + j;
            if (isbf) ((ushort*)y)[oi] = 0; else ((float*)y)[oi] = 0.0f;
        }
    }
}

extern "C" void kernel_launch(void* const* d_in, const int* in_sizes, int n_in,
                              void* d_out, int out_size, void* d_ws, size_t ws_size,
                              hipStream_t stream) {
    const void* inp = d_in[0];
    const void* Win = d_in[1];
    const void* bin = d_in[2];
    const void* Ws  = d_in[3];
    const void* bs  = d_in[4];
    const int*  len = (const int*)d_in[5];

    if (ws_size < WS_NEED) return;  // evidence: >=26.6 MB granted; need ~13.1 MB

    char* ws = (char*)d_ws;
    int* nbArr      = (int*)ws;
    unsigned* flags = (unsigned*)(ws + WS_NB);
    ushort* hbAll   = (ushort*)(ws + WS_HBOFF);
    ushort* wbf     = (ushort*)(ws + WS_WGT);

    hipMemsetAsync(d_ws, 0, WS_WGT, stream);   // nbArr/flags/h buffers = 0
    prep_nb<<<4, 256, 0, stream>>>(len, nbArr);
    conv_w<<<3168, 256, 0, stream>>>(Win, Ws, bs, wbf);
    lstm_main<<<NGRP * BPG, NTHREADS, 0, stream>>>(inp, bin, bs, len, d_out,
                                                   nbArr, flags, hbAll, wbf);
}